// Round 11
// baseline (364.189 us; speedup 1.0000x reference)
//
#include <hip/hip_runtime.h>

#define CHUNK 2048

// Fused: embed blocks [0,embed_blocks) + per-chunk bucket histogram blocks.
__global__ __launch_bounds__(256) void embed_count_kernel(
    const int* __restrict__ x, const float* __restrict__ emb, float* __restrict__ h0,
    const int* __restrict__ ei, int* __restrict__ pcount,
    int n_nodes, int n_edges, int n_bkt, int embed_blocks)
{
    __shared__ int cnt[512];
    int t = threadIdx.x;
    if ((int)blockIdx.x < embed_blocks) {
        int tt = blockIdx.x * 256 + t;
        if (tt < n_nodes * 16) {
            int n = tt >> 4, q = tt & 15;
            int xv = x[n];
            float4 v = {0.f, 0.f, 0.f, 0.f};
            if (xv != 0) v = *(const float4*)(emb + (size_t)xv * 64 + q * 4);
            *(float4*)(h0 + (size_t)n * 64 + q * 4) = v;
        }
        return;
    }
    int jb = blockIdx.x - embed_blocks;
    for (int b = t; b < 512; b += 256) cnt[b] = 0;
    __syncthreads();
    int base = jb * CHUNK;
#pragma unroll
    for (int i = 0; i < CHUNK / 256; ++i) {
        int e = base + i * 256 + t;
        if (e < n_edges) atomicAdd(&cnt[ei[n_edges + e] >> 7], 1);
    }
    __syncthreads();
    for (int b = t; b < n_bkt; b += 256) pcount[jb * n_bkt + b] = cnt[b];
}

// one block per bucket: exclusive scan over chunk counts -> pre, totals
__global__ __launch_bounds__(256) void colscan_kernel(
    const int* __restrict__ pcount, int* __restrict__ pre,
    int* __restrict__ totals, int* __restrict__ rowstartR,
    int n_chk, int n_bkt, int n_edges, int n_nodes)
{
    __shared__ int ps[256];
    int b = blockIdx.x, t = threadIdx.x;
    if (b == 0 && t == 0) rowstartR[4 * n_nodes] = n_edges;
    int v[4], s = 0;
#pragma unroll
    for (int i = 0; i < 4; ++i) {
        int jj = t * 4 + i;
        v[i] = (jj < n_chk) ? pcount[jj * n_bkt + b] : 0;
        s += v[i];
    }
    ps[t] = s;
    __syncthreads();
    for (int o = 1; o < 256; o <<= 1) {
        int u = (t >= o) ? ps[t - o] : 0;
        __syncthreads();
        ps[t] += u;
        __syncthreads();
    }
    int run = (t > 0) ? ps[t - 1] : 0;
#pragma unroll
    for (int i = 0; i < 4; ++i) {
        int jj = t * 4 + i;
        if (jj < n_chk) pre[jj * n_bkt + b] = run;
        run += v[i];
    }
    if (t == 255) totals[b] = run;
}

// 611 blocks x 2048 edges; deterministic bases (local scan of totals + pre row),
// LDS fill atomics only. Block 0 publishes bucket_start for the sort.
__global__ __launch_bounds__(256) void scatter_kernel(
    const int* __restrict__ ei, const int* __restrict__ et,
    const int* __restrict__ pre, const int* __restrict__ totals,
    int* __restrict__ esort, int* __restrict__ bucket_start,
    int n_edges, int n_bkt)
{
    __shared__ int bs[512], fill2[512], ps[256];
    int t = threadIdx.x, j = blockIdx.x;
    int a0 = (2 * t < n_bkt) ? totals[2 * t] : 0;
    int a1 = (2 * t + 1 < n_bkt) ? totals[2 * t + 1] : 0;
    ps[t] = a0 + a1;
    __syncthreads();
    for (int o = 1; o < 256; o <<= 1) {
        int u = (t >= o) ? ps[t - o] : 0;
        __syncthreads();
        ps[t] += u;
        __syncthreads();
    }
    int basex = (t > 0) ? ps[t - 1] : 0;
    bs[2 * t] = basex;
    bs[2 * t + 1] = basex + a0;
    fill2[t] = 0; fill2[t + 256] = 0;
    __syncthreads();
    if (j == 0) {
        for (int b = t; b < n_bkt; b += 256) bucket_start[b] = bs[b];
        if (t == 0) bucket_start[n_bkt] = n_edges;
    }
    for (int b = t; b < n_bkt; b += 256) bs[b] += pre[j * n_bkt + b];
    __syncthreads();
    int base = j * CHUNK;
#pragma unroll
    for (int i = 0; i < CHUNK / 256; ++i) {
        int e = base + i * 256 + t;
        if (e < n_edges) {
            int s = ei[e], d = ei[n_edges + e], r = et[e];
            int b = d >> 7;
            int pos = bs[b] + atomicAdd(&fill2[b], 1);
            esort[pos] = s | (r << 16) | ((d & 127) << 18);
        }
    }
}

// one block per bucket: 512-bin counting sort (bin = dstlo*4 + r),
// emits rowstartR[dst*4 + r].
__global__ __launch_bounds__(256) void bucket_sort_kernel(
    const int* __restrict__ bucket_start, int* __restrict__ esort,
    int* __restrict__ scratch, int* __restrict__ rowstartR, int n_nodes)
{
    __shared__ int cnt[512], off[512], fill[512], ps[256];
    int t = threadIdx.x, b = blockIdx.x;
    int s = bucket_start[b], e = bucket_start[b + 1];
    cnt[t] = 0; cnt[t + 256] = 0; fill[t] = 0; fill[t + 256] = 0;
    __syncthreads();
    int* scr = scratch + (size_t)b * 8192;
    for (int i = s + t; i < e; i += 256) {
        int p = esort[i];
        scr[i - s] = p;
        atomicAdd(&cnt[(p >> 16) & 0x1FF], 1);
    }
    __syncthreads();
    int a0 = cnt[2 * t], a1 = cnt[2 * t + 1];
    ps[t] = a0 + a1;
    __syncthreads();
    for (int o = 1; o < 256; o <<= 1) {
        int v = (t >= o) ? ps[t - o] : 0;
        __syncthreads();
        ps[t] += v;
        __syncthreads();
    }
    int basex = (t > 0) ? ps[t - 1] : 0;
    off[2 * t] = basex;
    off[2 * t + 1] = basex + a0;
    __syncthreads();
    int d0 = b * 128 + (2 * t >> 2);
    if (d0 < n_nodes) rowstartR[b * 512 + 2 * t] = s + off[2 * t];
    int d1 = b * 128 + ((2 * t + 1) >> 2);
    if (d1 < n_nodes) rowstartR[b * 512 + 2 * t + 1] = s + off[2 * t + 1];
    __syncthreads();
    for (int i = s + t; i < e; i += 256) {
        int p = scr[i - s];
        int bin = (p >> 16) & 0x1FF;
        int pos = s + off[bin] + atomicAdd(&fill[bin], 1);
        esort[pos] = p;
    }
}

// one wave per dst; rel-grouped sub-ranges; quarter-wave q takes a 4-edge
// window per 16-stride -> 4 independent row-loads in flight, 4 accumulators.
__global__ __launch_bounds__(256) void agg_kernel(
    const float* __restrict__ hin, const int* __restrict__ rowstartR,
    const int* __restrict__ esort, float* __restrict__ means, int n_nodes)
{
    int wid = (blockIdx.x * 256 + threadIdx.x) >> 6;
    int lane = threadIdx.x & 63;
    if (wid >= n_nodes) return;
    int q = lane >> 4;
    int c = lane & 15;
    int4 rs = *(const int4*)(rowstartR + wid * 4);

#pragma unroll
    for (int r = 0; r < 3; ++r) {
        int sR = (r == 0) ? rs.x : (r == 1) ? rs.y : rs.z;
        int eR = (r == 0) ? rs.y : (r == 1) ? rs.z : rs.w;
        float4 a0 = {0.f,0.f,0.f,0.f}, a1 = {0.f,0.f,0.f,0.f};
        float4 a2 = {0.f,0.f,0.f,0.f}, a3 = {0.f,0.f,0.f,0.f};
        int i = sR + 4 * q;
        for (; i + 4 <= eR; i += 16) {
            int p0 = esort[i], p1 = esort[i + 1], p2 = esort[i + 2], p3 = esort[i + 3];
            float4 v0 = *(const float4*)(hin + (size_t)(p0 & 0xFFFF) * 64 + c * 4);
            float4 v1 = *(const float4*)(hin + (size_t)(p1 & 0xFFFF) * 64 + c * 4);
            float4 v2 = *(const float4*)(hin + (size_t)(p2 & 0xFFFF) * 64 + c * 4);
            float4 v3 = *(const float4*)(hin + (size_t)(p3 & 0xFFFF) * 64 + c * 4);
            a0.x += v0.x; a0.y += v0.y; a0.z += v0.z; a0.w += v0.w;
            a1.x += v1.x; a1.y += v1.y; a1.z += v1.z; a1.w += v1.w;
            a2.x += v2.x; a2.y += v2.y; a2.z += v2.z; a2.w += v2.w;
            a3.x += v3.x; a3.y += v3.y; a3.z += v3.z; a3.w += v3.w;
        }
#pragma unroll
        for (int m = 0; m < 3; ++m) {   // tail: 1-3 edges in this quarter's window
            int ii = i + m;
            if (ii < eR) {
                int p = esort[ii];
                float4 v = *(const float4*)(hin + (size_t)(p & 0xFFFF) * 64 + c * 4);
                a0.x += v.x; a0.y += v.y; a0.z += v.z; a0.w += v.w;
            }
        }
        a0.x += a1.x + a2.x + a3.x; a0.y += a1.y + a2.y + a3.y;
        a0.z += a1.z + a2.z + a3.z; a0.w += a1.w + a2.w + a3.w;
        a0.x += __shfl_xor(a0.x, 16); a0.y += __shfl_xor(a0.y, 16);
        a0.z += __shfl_xor(a0.z, 16); a0.w += __shfl_xor(a0.w, 16);
        a0.x += __shfl_xor(a0.x, 32); a0.y += __shfl_xor(a0.y, 32);
        a0.z += __shfl_xor(a0.z, 32); a0.w += __shfl_xor(a0.w, 32);
        if (q == r) {
            float inv = 1.f / (float)max(eR - sR, 1);
            float4 m = {a0.x * inv, a0.y * inv, a0.z * inv, a0.w * inv};
            *(float4*)(means + (size_t)wid * 192 + r * 64 + c * 4) = m;
        }
    }
}

// thread = (2-node group, j-quad). W streamed through LDS in 8 slabs of 32
// rows (8 KB), double-buffered (16 KB). 1564 blocks -> ~6 blocks/CU
// (~24 waves/CU) vs 782/3 with the 4-node version: v-load latency hidden.
// Slabs 0-1 = wroot, 2-7 = wrel. LDS floor ~31 us; latency-limited before.
__global__ __launch_bounds__(256) void transform_kernel(
    const float* __restrict__ hin, const float* __restrict__ means,
    const float* __restrict__ wroot, const float* __restrict__ wrel,
    const float* __restrict__ bias, float* __restrict__ hout, int n_nodes)
{
    __shared__ float wsh[2][2048];   // 2 x 8 KB
    int t = threadIdx.x;
    int gt = blockIdx.x * 256 + t;
    int g = gt >> 4, q = gt & 15;
    int n0 = g * 2;
    bool act0 = (n0 < n_nodes);
    bool act1 = (n0 + 1 < n_nodes);
    int n1 = act1 ? (n0 + 1) : (n_nodes - 1);   // clamp for safe loads
    int n0c = act0 ? n0 : (n_nodes - 1);

    // stage slab 0
    {
        const float4* sp = (const float4*)wroot;
        float4* d = (float4*)wsh[0];
        d[t] = sp[t];
        d[t + 256] = sp[t + 256];
    }

    float4 b = *(const float4*)(bias + q * 4);
    float4 acc0 = b, acc1 = b;

    const float* hv0 = hin + (size_t)n0c * 64;
    const float* hv1 = hin + (size_t)n1 * 64;
    const float* mv0 = means + (size_t)n0c * 192;
    const float* mv1 = means + (size_t)n1 * 192;

    for (int s = 0; s < 8; ++s) {
        __syncthreads();   // slab s ready; buffer (s+1)&1 free
        if (s < 7) {
            int s2 = s + 1;
            const float4* sp = (s2 < 2) ? ((const float4*)wroot + s2 * 512)
                                        : ((const float4*)wrel + (s2 - 2) * 512);
            float4* d = (float4*)wsh[s2 & 1];
            d[t] = sp[t];
            d[t + 256] = sp[t + 256];
        }
        const float* vb0 = (s < 2) ? (hv0 + s * 32) : (mv0 + (s - 2) * 32);
        const float* vb1 = (s < 2) ? (hv1 + s * 32) : (mv1 + (s - 2) * 32);
        const float* wbuf = wsh[s & 1];
#pragma unroll
        for (int kq = 0; kq < 8; ++kq) {
            float4 v0 = *(const float4*)(vb0 + kq * 4);
            float4 v1 = *(const float4*)(vb1 + kq * 4);
#pragma unroll
            for (int kk = 0; kk < 4; ++kk) {
                float4 w = *(const float4*)(wbuf + (kq * 4 + kk) * 64 + q * 4);
                float s0 = kk == 0 ? v0.x : kk == 1 ? v0.y : kk == 2 ? v0.z : v0.w;
                float s1 = kk == 0 ? v1.x : kk == 1 ? v1.y : kk == 2 ? v1.z : v1.w;
                acc0.x = fmaf(s0, w.x, acc0.x); acc0.y = fmaf(s0, w.y, acc0.y);
                acc0.z = fmaf(s0, w.z, acc0.z); acc0.w = fmaf(s0, w.w, acc0.w);
                acc1.x = fmaf(s1, w.x, acc1.x); acc1.y = fmaf(s1, w.y, acc1.y);
                acc1.z = fmaf(s1, w.z, acc1.z); acc1.w = fmaf(s1, w.w, acc1.w);
            }
        }
    }
    if (act0) {
        float4 r0 = {fmaxf(acc0.x,0.f), fmaxf(acc0.y,0.f), fmaxf(acc0.z,0.f), fmaxf(acc0.w,0.f)};
        *(float4*)(hout + (size_t)n0 * 64 + q * 4) = r0;
    }
    if (act1) {
        float4 r1 = {fmaxf(acc1.x,0.f), fmaxf(acc1.y,0.f), fmaxf(acc1.z,0.f), fmaxf(acc1.w,0.f)};
        *(float4*)(hout + (size_t)(n0 + 1) * 64 + q * 4) = r1;
    }
}

// wave per graph: batch sorted -> binary-search bounds, mean, then 64->2 head
__global__ __launch_bounds__(256) void pool_kernel(
    const float* __restrict__ h2, const int* __restrict__ batch,
    const float* __restrict__ linw, const float* __restrict__ linb,
    float* __restrict__ out, int n_nodes, int n_graphs)
{
    int wid = (blockIdx.x * 256 + threadIdx.x) >> 6;
    int lane = threadIdx.x & 63;
    if (wid >= n_graphs) return;
    int g = wid;
    int lo = 0, hi = n_nodes;
    while (lo < hi) { int mid = (lo + hi) >> 1; if (batch[mid] < g) lo = mid + 1; else hi = mid; }
    int s = lo;
    lo = 0; hi = n_nodes;
    while (lo < hi) { int mid = (lo + hi) >> 1; if (batch[mid] < g + 1) lo = mid + 1; else hi = mid; }
    int e = lo;
    float sum = 0.f;
    for (int n = s; n < e; ++n) sum += h2[(size_t)n * 64 + lane];
    float mean = sum / (float)max(e - s, 1);
    float d0 = mean * linw[lane * 2 + 0];
    float d1 = mean * linw[lane * 2 + 1];
    for (int off = 32; off > 0; off >>= 1) {
        d0 += __shfl_down(d0, off);
        d1 += __shfl_down(d1, off);
    }
    if (lane == 0) {
        out[g * 2 + 0] = d0 + linb[0];
        out[g * 2 + 1] = d1 + linb[1];
    }
}

extern "C" void kernel_launch(void* const* d_in, const int* in_sizes, int n_in,
                              void* d_out, int out_size, void* d_ws, size_t ws_size,
                              hipStream_t stream)
{
    const int*   x      = (const int*)d_in[0];
    const int*   ei     = (const int*)d_in[1];
    const int*   et     = (const int*)d_in[2];
    const int*   batch  = (const int*)d_in[3];
    const float* emb    = (const float*)d_in[4];
    const float* w1rel  = (const float*)d_in[5];
    const float* w1root = (const float*)d_in[6];
    const float* b1     = (const float*)d_in[7];
    const float* w2rel  = (const float*)d_in[8];
    const float* w2root = (const float*)d_in[9];
    const float* b2     = (const float*)d_in[10];
    const float* linw   = (const float*)d_in[11];
    const float* linb   = (const float*)d_in[12];
    float* out = (float*)d_out;

    const int N = in_sizes[0];            // 50000
    const int E = in_sizes[2];            // 1250000
    const int G = out_size / 2;           // 512
    const int NBKT = (N + 127) >> 7;      // 391
    const int NCHK = (E + CHUNK - 1) / CHUNK;  // 611

    float* hA        = (float*)d_ws;                     // [N][64]
    float* hB        = hA + (size_t)N * 64;              // [N][64]
    float* means     = hB + (size_t)N * 64;              // [N][192]
    int*   esort     = (int*)(means + (size_t)N * 192);  // [E]
    int*   rowstartR = esort + E;                        // [4N+4]
    int*   bucket_start = rowstartR + 4 * N + 4;         // [NBKT+1]
    int*   totals    = bucket_start + NBKT + 1;          // [NBKT]
    int*   scratch   = (int*)means;                      // sort scratch (12.8 MB)
    int*   pcount    = (int*)means + 4 * 1024 * 1024;    // [NCHK*NBKT] (~1 MB)
    int*   pre       = (int*)means + 5 * 1024 * 1024;    // [NCHK*NBKT]

    int embedBlocks = (N * 16 + 255) / 256;              // 3125
    embed_count_kernel<<<embedBlocks + NCHK, 256, 0, stream>>>(
        x, emb, hA, ei, pcount, N, E, NBKT, embedBlocks);
    colscan_kernel<<<NBKT, 256, 0, stream>>>(pcount, pre, totals, rowstartR, NCHK, NBKT, E, N);
    scatter_kernel<<<NCHK, 256, 0, stream>>>(ei, et, pre, totals, esort, bucket_start, E, NBKT);
    bucket_sort_kernel<<<NBKT, 256, 0, stream>>>(bucket_start, esort, scratch, rowstartR, N);

    int aggBlocks = (N * 64 + 255) / 256;                // one wave per dst
    int tfBlocks  = ((N + 1) / 2 * 16 + 255) / 256;      // 2 nodes per thread
    agg_kernel<<<aggBlocks, 256, 0, stream>>>(hA, rowstartR, esort, means, N);
    transform_kernel<<<tfBlocks, 256, 0, stream>>>(hA, means, w1root, w1rel, b1, hB, N);
    agg_kernel<<<aggBlocks, 256, 0, stream>>>(hB, rowstartR, esort, means, N);
    transform_kernel<<<tfBlocks, 256, 0, stream>>>(hB, means, w2root, w2rel, b2, hA, N);

    pool_kernel<<<(G * 64 + 255) / 256, 256, 0, stream>>>(hA, batch, linw, linb, out, N, G);
}